// Round 5
// baseline (962.254 us; speedup 1.0000x reference)
//
#include <hip/hip_runtime.h>
#include <hip/hip_bf16.h>

#define TOKENS 32768
#define NEXP   16
#define HID    2048
#define IMD    1408
#define BM 256
#define BK 64

typedef __bf16 bf16x8 __attribute__((ext_vector_type(8)));
typedef float  f32x4  __attribute__((ext_vector_type(4)));
typedef unsigned short u16x8 __attribute__((ext_vector_type(8)));

using gptr1_t = const __attribute__((address_space(1))) void*;
using lptr3_t = __attribute__((address_space(3))) void*;

static __device__ __forceinline__ unsigned short f2bf(float f) {
  unsigned int x = __builtin_bit_cast(unsigned int, f);
  x += 0x7fffu + ((x >> 16) & 1u);   // round-to-nearest-even
  return (unsigned short)(x >> 16);
}
static __device__ __forceinline__ float bf2f(unsigned short u) {
  unsigned int x = ((unsigned int)u) << 16;
  return __builtin_bit_cast(float, x);
}
static __device__ __forceinline__ void gload16(const void* g, void* l) {
  __builtin_amdgcn_global_load_lds((gptr1_t)g, (lptr3_t)l, 16, 0, 0);
}
static __device__ __forceinline__ void vwait(int n) {
  switch (n) {
    case 0:  asm volatile("s_waitcnt vmcnt(0)" ::: "memory"); break;
    case 2:  asm volatile("s_waitcnt vmcnt(2)" ::: "memory"); break;
    case 4:  asm volatile("s_waitcnt vmcnt(4)" ::: "memory"); break;
    default: asm volatile("s_waitcnt vmcnt(6)" ::: "memory"); break;
  }
}

// ---------------- f32 -> bf16 straight convert (x) ----------------
__global__ __launch_bounds__(256)
void convert_kernel(const float* __restrict__ in, unsigned short* __restrict__ out, size_t n)
{
  size_t i = ((size_t)blockIdx.x * blockDim.x + threadIdx.x) * 8;
  if (i >= n) return;
  float4 a = *(const float4*)(in + i);
  float4 b = *(const float4*)(in + i + 4);
  u16x8 o;
  o[0] = f2bf(a.x); o[1] = f2bf(a.y); o[2] = f2bf(a.z); o[3] = f2bf(a.w);
  o[4] = f2bf(b.x); o[5] = f2bf(b.y); o[6] = f2bf(b.z); o[7] = f2bf(b.w);
  *(u16x8*)(out + i) = o;
}

// ------------- f32 [E][K][N] -> bf16 [E][N][K] transpose-convert -------------
__global__ __launch_bounds__(256)
void transpose_conv_kernel(const float* __restrict__ in, unsigned short* __restrict__ out,
                           int K, int N)
{
  __shared__ float tile[32][33];
  const int e = blockIdx.z;
  const float* ip = in + (size_t)e * K * N;
  unsigned short* op = out + (size_t)e * K * N;
  const int c0 = blockIdx.x * 32, r0 = blockIdx.y * 32;
  const int tx = threadIdx.x, ty = threadIdx.y;
#pragma unroll
  for (int i = 0; i < 4; ++i)
    tile[ty + 8 * i][tx] = ip[(size_t)(r0 + ty + 8 * i) * N + c0 + tx];
  __syncthreads();
#pragma unroll
  for (int i = 0; i < 4; ++i)
    op[(size_t)(c0 + ty + 8 * i) * K + r0 + tx] = f2bf(tile[tx][ty + 8 * i]);
}

// ======== grouped GEMM, 256x256 tile, BK=64, read/MFMA-overlapped ========
// Per K-tile: 2 barrier segments (mh0 | mh1), double register sets so each
// phase's ds_reads issue BEFORE the previous phase's MFMA cluster (in-order
// issue => reads fly under the matrix pipe). Counted vmcnt only; barriers
// publish staged chunks cross-wave:
//   end-barrier (vwait(2)): chunks B0,B1,A0 of next tile published
//   mid-barrier (vwait(4)): chunk A1 of current tile published
// LDS row permutation + slot swizzle identical to round 4 (verified).
// MODE 0: fused gate+up, B cols interleaved by 16 (even=gate, odd=up):
//         h = bf16(silu(g)*u). MODE 1: down, BN=256, f32 out.
template<int MODE>
__global__ __launch_bounds__(512, 2)
void gemm_kernel(const unsigned short* __restrict__ A,
                 const unsigned short* __restrict__ B0m,
                 const unsigned short* __restrict__ B1m,
                 unsigned short* __restrict__ Hc,
                 float* __restrict__ Cf,
                 const int* __restrict__ gs,
                 int K, int N)
{
  constexpr int NRT = TOKENS / BM;   // 128 row tiles

  __shared__ __align__(16) unsigned short lA[2][256 * 64];  // 64 KiB
  __shared__ __align__(16) unsigned short lB[2][256 * 64];  // 64 KiB

  // bijective XCD swizzle; row-tile fastest -> per-XCD chunk shares a B panel
  const int nwg = gridDim.x;
  const int q = nwg >> 3;
  const int wgid = (blockIdx.x & 7) * q + (blockIdx.x >> 3);
  const int rt = wgid % NRT;
  const int ct = wgid / NRT;
  const int row0 = rt * BM;

  int e = 0;
  { int a0 = 0;
    for (int i = 0; i < NEXP; ++i) { int s = gs[i]; if (row0 < a0 + s) { e = i; break; } a0 += s; } }

  const unsigned short* Ap = A + (size_t)row0 * K;
  const unsigned short* Bg = B0m + (size_t)e * N * K;
  const unsigned short* Bu = (MODE == 0) ? (B1m + (size_t)e * N * K) : nullptr;

  const int tid  = threadIdx.x;
  const int lane = tid & 63, wave = tid >> 6;
  const int wr = wave >> 2, wc = wave & 3;   // 2 M-waves x 4 N-waves, 128x64/wave
  const int fr = lane & 15, fq = lane >> 4;

  // swizzled fragment-read slot (elems): slot = (kk*4+fq) ^ (fr&7)
  const int csw0 = ((0 * 4 + fq) ^ (fr & 7)) * 8;
  const int csw1 = ((1 * 4 + fq) ^ (fr & 7)) * 8;

  // staging: pre-swizzled global column (both-sides swizzle, rule #21)
  const int r8   = lane >> 3;
  const int slog = ((lane & 7) ^ (r8 & 7)) * 8;

  const int nt = K / BK;

  f32x4 acc[8][4] = {};
  bf16x8 aX[4], aY[4], b0[4], b1[4];

  // stage one 128-row chunk (2 x gload16/thread).
  // chunk: 0 = B_nh0, 1 = B_nh1, 2 = A_mh0, 3 = A_mh1
  auto stage = [&](int chunk, int tt) {
    const int buf = tt & 1;
    const int k0 = tt * BK;
#pragma unroll
    for (int w = 0; w < 2; ++w) {
      if (chunk >= 2) {
        const int mh = chunk - 2;
        unsigned short* ldst = &lA[buf][(mh * 128 + w * 64 + wave * 8) * 64];
        const int grow = w * 128 + mh * 64 + wave * 8 + r8;
        gload16(Ap + (size_t)grow * K + k0 + slog, ldst);
      } else {
        const int h = chunk;
        unsigned short* ldst = &lB[buf][(h * 128 + w * 64 + wave * 8) * 64];
        const int rem = w * 64 + wave * 8 + r8;     // 0..127
        const int wcs = rem >> 5, rr = rem & 31;
        if constexpr (MODE == 0) {
          const int gcol = ct * 128 + (wcs * 2 + h) * 16 + (rr & 15);
          const unsigned short* mb = ((rr >> 4) & 1) ? Bu : Bg;
          gload16(mb + (size_t)gcol * K + k0 + slog, ldst);
        } else {
          const int gcol = ct * 256 + wcs * 64 + h * 32 + rr;
          gload16(Bg + (size_t)gcol * K + k0 + slog, ldst);
        }
      }
    }
  };

  auto readA = [&](bf16x8* d, const unsigned short* base, int mh, int kk) {
    const int csw = kk ? csw1 : csw0;
#pragma unroll
    for (int mf = 0; mf < 4; ++mf)
      d[mf] = *(const bf16x8*)(base + (mh * 128 + wr * 64 + mf * 16 + fr) * 64 + csw);
  };
  auto readB = [&](bf16x8* d, const unsigned short* base, int kk) {
    const int csw = kk ? csw1 : csw0;
#pragma unroll
    for (int nf = 0; nf < 4; ++nf)
      d[nf] = *(const bf16x8*)(base + ((nf >> 1) * 128 + wc * 32 + (nf & 1) * 16 + fr) * 64 + csw);
  };
  auto mfma16 = [&](int ab, const bf16x8* a, const bf16x8* b) {
    __builtin_amdgcn_s_setprio(1);
#pragma unroll
    for (int mf = 0; mf < 4; ++mf)
#pragma unroll
      for (int nf = 0; nf < 4; ++nf)
        acc[ab + mf][nf] =
            __builtin_amdgcn_mfma_f32_16x16x32_bf16(a[mf], b[nf], acc[ab + mf][nf], 0, 0, 0);
    __builtin_amdgcn_s_setprio(0);
  };

  // prologue: tile 0 staged; B0,B1,A0 published, A1 kept in flight
  stage(0, 0); stage(1, 0); stage(2, 0); stage(3, 0);
  vwait(2);
  __builtin_amdgcn_s_barrier();
  __builtin_amdgcn_sched_barrier(0);
  readA(aX, lA[0], 0, 0);
  readB(b0, lB[0], 0);

  for (int t = 0; t < nt; ++t) {
    const int cur = t & 1;
    const bool more = (t + 1 < nt);
    const unsigned short* Ab = lA[cur];
    const unsigned short* Bb = lB[cur];

    // --- segment 1 (mh0): phases (mh0,k0), (mh0,k1) ---
    readA(aY, Ab, 0, 1);          // reads for phase 2 fly under MFMA of phase 1
    readB(b1, Bb, 1);
    if (more) stage(0, t + 1);
    mfma16(0, aX, b0);            // (mh0,k0)
    if (more) stage(1, t + 1);
    mfma16(0, aY, b1);            // (mh0,k1)

    // mid-barrier: publish chunk A1(t) cross-wave (own-drain + barrier)
    vwait(more ? 4 : 0);
    __builtin_amdgcn_s_barrier();
    __builtin_amdgcn_sched_barrier(0);

    // --- segment 2 (mh1): phases (mh1,k0), (mh1,k1) ---
    readA(aX, Ab, 1, 0);
    if (more) stage(2, t + 1);
    mfma16(4, aX, b0);            // (mh1,k0)
    readA(aY, Ab, 1, 1);
    if (more) stage(3, t + 1);
    mfma16(4, aY, b1);            // (mh1,k1)

    if (more) {
      // end-barrier: publish chunks B0,B1,A0(t+1); A1(t+1) stays in flight
      vwait(2);
      __builtin_amdgcn_s_barrier();
      __builtin_amdgcn_sched_barrier(0);
      readA(aX, lA[cur ^ 1], 0, 0);
      readB(b0, lB[cur ^ 1], 0);
    }
  }

  // epilogue. C/D frag layout: col = lane&15, row = fq*4 + reg (m89-verified)
  // acc[mi][nf]: global row = row0 + wr*128 + (mi>>2)*64 + (mi&3)*16 + fq*4 + reg
#pragma unroll
  for (int mi = 0; mi < 8; ++mi) {
    const int rowb = row0 + wr * 128 + (mi >> 2) * 64 + (mi & 3) * 16 + fq * 4;
    if constexpr (MODE == 0) {
#pragma unroll
      for (int m2 = 0; m2 < 2; ++m2) {
        const int col = ct * 128 + (wc * 2 + m2) * 16 + fr;
        f32x4 g = acc[mi][2 * m2], u = acc[mi][2 * m2 + 1];
#pragma unroll
        for (int r = 0; r < 4; ++r) {
          float gv = g[r];
          float s = gv / (1.f + __expf(-gv)) * u[r];
          Hc[(size_t)(rowb + r) * N + col] = f2bf(s);
        }
      }
    } else {
#pragma unroll
      for (int nf = 0; nf < 4; ++nf) {
        const int col = ct * 256 + wc * 64 + nf * 16 + fr;
        f32x4 v = acc[mi][nf];
#pragma unroll
        for (int r = 0; r < 4; ++r)
          Cf[(size_t)(rowb + r) * N + col] = v[r];
      }
    }
  }
}

extern "C" void kernel_launch(void* const* d_in, const int* in_sizes, int n_in,
                              void* d_out, int out_size, void* d_ws, size_t ws_size,
                              hipStream_t stream)
{
  const float* x  = (const float*)d_in[0];
  const float* wg = (const float*)d_in[1];
  const float* wu = (const float*)d_in[2];
  const float* wd = (const float*)d_in[3];
  const int*   gs = (const int*)d_in[4];
  float* out = (float*)d_out;

  const size_t SZ_XB = (size_t)TOKENS * HID * 2;        // 134,217,728
  const size_t SZ_W  = (size_t)NEXP * HID * IMD * 2;    //  92,274,688
  const size_t SZ_H  = (size_t)TOKENS * IMD * 2;        //  92,274,688
  if (ws_size < SZ_XB + 2 * SZ_W + SZ_H) return;        // (411 MB proven available)

  char* ws = (char*)d_ws;
  unsigned short* xb  = (unsigned short*)ws;
  unsigned short* wTg = (unsigned short*)(ws + SZ_XB);
  unsigned short* wTu = (unsigned short*)(ws + SZ_XB + SZ_W);
  unsigned short* h   = (unsigned short*)(ws + SZ_XB + 2 * SZ_W);

  const int cvt_grid = (int)(((size_t)TOKENS * HID) / (256 * 8));
  convert_kernel<<<cvt_grid, 256, 0, stream>>>(x, xb, (size_t)TOKENS * HID);

  transpose_conv_kernel<<<dim3(IMD / 32, HID / 32, NEXP), dim3(32, 8), 0, stream>>>(wg, wTg, HID, IMD);
  transpose_conv_kernel<<<dim3(IMD / 32, HID / 32, NEXP), dim3(32, 8), 0, stream>>>(wu, wTu, HID, IMD);
  gemm_kernel<0><<<(TOKENS / BM) * (IMD / 128), 512, 0, stream>>>(
      xb, wTg, wTu, h, nullptr, gs, HID, IMD);

  transpose_conv_kernel<<<dim3(HID / 32, IMD / 32, NEXP), dim3(32, 8), 0, stream>>>(wd, wTg, IMD, HID);
  gemm_kernel<1><<<(TOKENS / BM) * (HID / 256), 512, 0, stream>>>(
      h, wTg, nullptr, nullptr, out, gs, IMD, HID);
}

// Round 6
// 876.126 us; speedup vs baseline: 1.0983x; 1.0983x over previous
//
#include <hip/hip_runtime.h>
#include <hip/hip_bf16.h>

#define TOKENS 32768
#define NEXP   16
#define HID    2048
#define IMD    1408
#define BM 256
#define BK 64

typedef __bf16 bf16x8 __attribute__((ext_vector_type(8)));
typedef float  f32x4  __attribute__((ext_vector_type(4)));
typedef float  f32x16 __attribute__((ext_vector_type(16)));
typedef unsigned short u16x8 __attribute__((ext_vector_type(8)));

using gptr1_t = const __attribute__((address_space(1))) void*;
using lptr3_t = __attribute__((address_space(3))) void*;

static __device__ __forceinline__ unsigned short f2bf(float f) {
  unsigned int x = __builtin_bit_cast(unsigned int, f);
  x += 0x7fffu + ((x >> 16) & 1u);   // round-to-nearest-even
  return (unsigned short)(x >> 16);
}
static __device__ __forceinline__ float bf2f(unsigned short u) {
  unsigned int x = ((unsigned int)u) << 16;
  return __builtin_bit_cast(float, x);
}
static __device__ __forceinline__ void gload16(const void* g, void* l) {
  __builtin_amdgcn_global_load_lds((gptr1_t)g, (lptr3_t)l, 16, 0, 0);
}
static __device__ __forceinline__ void vwait0() {
  asm volatile("s_waitcnt vmcnt(0)" ::: "memory");
}
static __device__ __forceinline__ void lgkm6() {
  asm volatile("s_waitcnt lgkmcnt(6)" ::: "memory");
}
static __device__ __forceinline__ void lgkm0() {
  asm volatile("s_waitcnt lgkmcnt(0)" ::: "memory");
}
// raw LDS read: compiler cannot track/merge waits on this (we own lgkmcnt)
static __device__ __forceinline__ f32x4 ds128(unsigned addr) {
  f32x4 d;
  asm volatile("ds_read_b128 %0, %1" : "=&v"(d) : "v"(addr));
  return d;
}

// ---------------- f32 -> bf16 straight convert (x) ----------------
__global__ __launch_bounds__(256)
void convert_kernel(const float* __restrict__ in, unsigned short* __restrict__ out, size_t n)
{
  size_t i = ((size_t)blockIdx.x * blockDim.x + threadIdx.x) * 8;
  if (i >= n) return;
  float4 a = *(const float4*)(in + i);
  float4 b = *(const float4*)(in + i + 4);
  u16x8 o;
  o[0] = f2bf(a.x); o[1] = f2bf(a.y); o[2] = f2bf(a.z); o[3] = f2bf(a.w);
  o[4] = f2bf(b.x); o[5] = f2bf(b.y); o[6] = f2bf(b.z); o[7] = f2bf(b.w);
  *(u16x8*)(out + i) = o;
}

// ------------- f32 [E][K][N] -> bf16 [E][N][K] transpose-convert -------------
__global__ __launch_bounds__(256)
void transpose_conv_kernel(const float* __restrict__ in, unsigned short* __restrict__ out,
                           int K, int N)
{
  __shared__ float tile[32][33];
  const int e = blockIdx.z;
  const float* ip = in + (size_t)e * K * N;
  unsigned short* op = out + (size_t)e * K * N;
  const int c0 = blockIdx.x * 32, r0 = blockIdx.y * 32;
  const int tx = threadIdx.x, ty = threadIdx.y;
#pragma unroll
  for (int i = 0; i < 4; ++i)
    tile[ty + 8 * i][tx] = ip[(size_t)(r0 + ty + 8 * i) * N + c0 + tx];
  __syncthreads();
#pragma unroll
  for (int i = 0; i < 4; ++i)
    op[(size_t)(c0 + ty + 8 * i) * K + r0 + tx] = f2bf(tile[tx][ty + 8 * i]);
}

// ======== grouped GEMM, 256x256 tile, BK=64, 32x32x16 MFMA, asm-DS pipeline ===
// Per K-tile per wave: 4 kk-steps, each {6 asm ds_read_b128} pipelined 2-deep
// against {8 MFMA} clusters with counted lgkmcnt(6) (in-order DS completion).
// ONE s_barrier per tile; t+1 staging (8 global_load_lds) issued mid-tile,
// drained by vmcnt(0) at the tile boundary (~1000+ cyc of cover).
// Swizzle (both sides, rule #21): 16B slot s of row r holds global slot
// s ^ (r&7); staged via pre-swizzled per-lane source column.
// MODE 0: fused gate+up, B cols interleaved by 32 (nf0=gate, nf1=up):
//         h = bf16(silu(g)*u), h is [TOKENS][N=IMD].
// MODE 1: down: Cf = acc, [TOKENS][N=HID].
template<int MODE, int K, int N>
__global__ __launch_bounds__(512, 2)
void gemm_kernel(const unsigned short* __restrict__ A,
                 const unsigned short* __restrict__ B0m,
                 const unsigned short* __restrict__ B1m,
                 unsigned short* __restrict__ Hc,
                 float* __restrict__ Cf,
                 const int* __restrict__ gs)
{
  constexpr int NRT = TOKENS / BM;   // 128 row tiles
  constexpr int nt  = K / BK;

  __shared__ __align__(16) unsigned short lA[2][256 * 64];  // 64 KiB
  __shared__ __align__(16) unsigned short lB[2][256 * 64];  // 64 KiB

  // bijective XCD swizzle; row-tile fastest -> per-XCD chunk shares a B panel
  const int nwg = gridDim.x;
  const int qq = nwg >> 3;
  const int wgid = (blockIdx.x & 7) * qq + (blockIdx.x >> 3);
  const int rt = wgid % NRT;
  const int ct = wgid / NRT;
  const int row0 = rt * BM;

  int e = 0;
  { int a0 = 0;
    for (int i = 0; i < NEXP; ++i) { int s = gs[i]; if (row0 < a0 + s) { e = i; break; } a0 += s; } }

  const unsigned short* Ap = A + (size_t)row0 * K;
  const unsigned short* Bg = B0m + (size_t)e * N * K;
  const unsigned short* Bu = (MODE == 0) ? (B1m + (size_t)e * N * K) : nullptr;

  const int tid  = threadIdx.x;
  const int lane = tid & 63, wave = tid >> 6;
  const int wr = wave >> 2, wc = wave & 3;   // 2 M-waves x 4 N-waves, 128x64/wave
  const int l31 = lane & 31, hi = lane >> 5, l7 = lane & 7;
  const int r8 = lane >> 3;
  const int slog = ((lane & 7) ^ r8) * 8;    // pre-swizzled staging source column

  // swizzled read slot byte-offsets per kk: slot = (kk*2+hi) ^ (row&7=l7)
  const unsigned sw0 = (unsigned)(((0 + hi) ^ l7) * 16);
  const unsigned sw1 = (unsigned)(((2 + hi) ^ l7) * 16);
  const unsigned sw2 = (unsigned)(((4 + hi) ^ l7) * 16);
  const unsigned sw3 = (unsigned)(((6 + hi) ^ l7) * 16);

  // LDS byte bases (low 32 bits of generic pointer = LDS offset)
  const unsigned lAb = (unsigned)(unsigned long long)(const void*)&lA[0][0];
  const unsigned lBb = (unsigned)(unsigned long long)(const void*)&lB[0][0];
  const unsigned aRow = lAb + (unsigned)((wr * 128 + l31) * 128);  // row stride 128B
  const unsigned bRow = lBb + (unsigned)((wc * 64 + l31) * 128);

  f32x16 acc[4][2] = {};

  // stage one 128-row chunk (2 x gload16/thread).
  // chunk: 0 = B rows 0..127, 1 = B rows 128..255, 2 = A rows 0..127, 3 = A 128..255
  auto stage = [&](int chunk, int tt) {
    const int buf = tt & 1;
    const int k0 = tt * BK;
#pragma unroll
    for (int w = 0; w < 2; ++w) {
      if (chunk >= 2) {
        const int c = chunk - 2;
        unsigned short* ldst = &lA[buf][(c * 128 + w * 64 + wave * 8) * 64];
        const int grow = c * 128 + w * 64 + wave * 8 + r8;
        gload16(Ap + (size_t)grow * K + k0 + slog, ldst);
      } else {
        unsigned short* ldst = &lB[buf][(chunk * 128 + w * 64 + wave * 8) * 64];
        const int rem = w * 64 + wave * 8 + r8;       // 0..127
        const int v = chunk * 128 + rem;              // B LDS row 0..255
        if constexpr (MODE == 0) {
          const int wcq = v >> 6, p = (v >> 5) & 1, i = v & 31;
          const unsigned short* mb = p ? Bu : Bg;
          const int gcol = ct * 128 + wcq * 32 + i;
          gload16(mb + (size_t)gcol * K + k0 + slog, ldst);
        } else {
          const int gcol = ct * 256 + v;
          gload16(Bg + (size_t)gcol * K + k0 + slog, ldst);
        }
      }
    }
  };

  auto rdA = [&](f32x4* d, unsigned sw, unsigned bufoff) {
#pragma unroll
    for (int m = 0; m < 4; ++m)
      d[m] = ds128(aRow + bufoff + (unsigned)(m * 4096) + sw);
  };
  auto rdB = [&](f32x4* d, unsigned sw, unsigned bufoff) {
    d[0] = ds128(bRow + bufoff + sw);
    d[1] = ds128(bRow + bufoff + 4096u + sw);
  };
  auto cluster = [&](const f32x4* a4, const f32x4* b2) {
    __builtin_amdgcn_sched_barrier(0);
    __builtin_amdgcn_s_setprio(1);
#pragma unroll
    for (int m = 0; m < 4; ++m)
#pragma unroll
      for (int n2 = 0; n2 < 2; ++n2)
        acc[m][n2] = __builtin_amdgcn_mfma_f32_32x32x16_bf16(
            __builtin_bit_cast(bf16x8, a4[m]), __builtin_bit_cast(bf16x8, b2[n2]),
            acc[m][n2], 0, 0, 0);
    __builtin_amdgcn_s_setprio(0);
    __builtin_amdgcn_sched_barrier(0);
  };

  // prologue: tile 0 staged and published
  stage(0, 0); stage(1, 0); stage(2, 0); stage(3, 0);
  vwait0();
  __builtin_amdgcn_s_barrier();

  f32x4 aS0[4], bS0[2], aS1[4], bS1[2], aS2[4], bS2[2];

  for (int t = 0; t < nt; ++t) {
    const unsigned bufoff = (unsigned)((t & 1) * 32768);
    const bool more = (t + 1 < nt);

    rdA(aS0, sw0, bufoff); rdB(bS0, sw0, bufoff);   // kk0
    rdA(aS1, sw1, bufoff); rdB(bS1, sw1, bufoff);   // kk1
    lgkm6();                                        // kk0 complete, kk1 in flight
    cluster(aS0, bS0);
    if (more) { stage(0, t + 1); stage(1, t + 1); }
    rdA(aS2, sw2, bufoff); rdB(bS2, sw2, bufoff);   // kk2
    lgkm6();                                        // kk1 complete
    cluster(aS1, bS1);
    if (more) { stage(2, t + 1); stage(3, t + 1); }
    rdA(aS0, sw3, bufoff); rdB(bS0, sw3, bufoff);   // kk3 (reuse set 0)
    lgkm6();                                        // kk2 complete
    cluster(aS2, bS2);
    lgkm0();                                        // kk3 complete
    cluster(aS0, bS0);

    vwait0();                                       // own t+1 stages landed
    __builtin_amdgcn_s_barrier();                   // publish LDS[t+1 buffer]
  }

  // epilogue. 32x32 C/D layout (m74/m101): col = lane&31,
  // row = (reg&3) + 8*(reg>>2) + 4*(lane>>5)
#pragma unroll
  for (int m = 0; m < 4; ++m) {
    const int rowb = row0 + wr * 128 + m * 32 + 4 * hi;
    if constexpr (MODE == 0) {
      const int col = ct * 128 + wc * 32 + l31;
      f32x16 g = acc[m][0], u = acc[m][1];
#pragma unroll
      for (int r = 0; r < 16; ++r) {
        const int row = rowb + (r & 3) + 8 * (r >> 2);
        float gv = g[r];
        float s = gv / (1.f + __expf(-gv)) * u[r];
        Hc[(size_t)row * N + col] = f2bf(s);
      }
    } else {
#pragma unroll
      for (int n2 = 0; n2 < 2; ++n2) {
        const int col = ct * 256 + wc * 64 + n2 * 32 + l31;
        f32x16 v = acc[m][n2];
#pragma unroll
        for (int r = 0; r < 16; ++r) {
          const int row = rowb + (r & 3) + 8 * (r >> 2);
          Cf[(size_t)row * N + col] = v[r];
        }
      }
    }
  }
}

extern "C" void kernel_launch(void* const* d_in, const int* in_sizes, int n_in,
                              void* d_out, int out_size, void* d_ws, size_t ws_size,
                              hipStream_t stream)
{
  const float* x  = (const float*)d_in[0];
  const float* wg = (const float*)d_in[1];
  const float* wu = (const float*)d_in[2];
  const float* wd = (const float*)d_in[3];
  const int*   gs = (const int*)d_in[4];
  float* out = (float*)d_out;

  const size_t SZ_XB = (size_t)TOKENS * HID * 2;        // 134,217,728
  const size_t SZ_W  = (size_t)NEXP * HID * IMD * 2;    //  92,274,688
  const size_t SZ_H  = (size_t)TOKENS * IMD * 2;        //  92,274,688
  if (ws_size < SZ_XB + 2 * SZ_W + SZ_H) return;        // (411 MB proven available)

  char* ws = (char*)d_ws;
  unsigned short* xb  = (unsigned short*)ws;
  unsigned short* wTg = (unsigned short*)(ws + SZ_XB);
  unsigned short* wTu = (unsigned short*)(ws + SZ_XB + SZ_W);
  unsigned short* h   = (unsigned short*)(ws + SZ_XB + 2 * SZ_W);

  const int cvt_grid = (int)(((size_t)TOKENS * HID) / (256 * 8));
  convert_kernel<<<cvt_grid, 256, 0, stream>>>(x, xb, (size_t)TOKENS * HID);

  transpose_conv_kernel<<<dim3(IMD / 32, HID / 32, NEXP), dim3(32, 8), 0, stream>>>(wg, wTg, HID, IMD);
  transpose_conv_kernel<<<dim3(IMD / 32, HID / 32, NEXP), dim3(32, 8), 0, stream>>>(wu, wTu, HID, IMD);
  gemm_kernel<0, HID, IMD><<<(TOKENS / BM) * (IMD / 128), 512, 0, stream>>>(
      xb, wTg, wTu, h, nullptr, gs);

  transpose_conv_kernel<<<dim3(HID / 32, IMD / 32, NEXP), dim3(32, 8), 0, stream>>>(wd, wTg, IMD, HID);
  gemm_kernel<1, IMD, HID><<<(TOKENS / BM) * (HID / 256), 512, 0, stream>>>(
      h, wTg, nullptr, nullptr, out, gs);
}